// Round 11
// baseline (74.930 us; speedup 1.0000x reference)
//
#include <hip/hip_runtime.h>

#define HW   4096      // 64*64
#define NC   256
#define NTB  24        // 3 tensors * 8 batches
#define TOPK 2048      // max(1, int(0.5 * 4096))

typedef float vf4 __attribute__((ext_vector_type(4)));

// ---------------------------------------------------------------------------
// K1 (pass A): imp[tb][hw] = (sum_{c seq} |x|)/256, bitwise == np order.
// R5-proven: scalar chain/thread, 384 blocks x 256, unroll-32. ~3.5 us
// (inputs L3-resident in steady-state replay; R7/R8 probe algebra).
// ---------------------------------------------------------------------------
__global__ __launch_bounds__(256) void k_imp(const float* __restrict__ i0,
                                             const float* __restrict__ i1,
                                             const float* __restrict__ i2,
                                             float* __restrict__ imp) {
  int tid = blockIdx.x * 256 + threadIdx.x;   // 0 .. 98303
  int hw  = tid & (HW - 1);
  int tb  = tid >> 12;                        // 0 .. 23
  int t   = tb >> 3;
  const float* base = (t == 0 ? i0 : (t == 1 ? i1 : i2));
  const float* p = base + (size_t)(tb & 7) * NC * HW + hw;
  float s = 0.f;
#pragma unroll 32
  for (int c = 0; c < NC; ++c) s += fabsf(p[c * HW]);  // program order per chain
  imp[tid] = s * (1.0f / 256.0f);             // exact pow2 == /256.0
}

// ---------------------------------------------------------------------------
// K2 (select+apply fused, SPILL-PROOFED): __launch_bounds__(256, 1) grants
// up to 256 VGPRs -> u[64] provably register-resident. (R9: default LB(256)
// allocated 56 VGPR < u[64] -> scratch thrash, 66 us. R10: LB(64) likely
// same disease, ~52 us inferred. Select math itself is absmax-0 proven.)
// 768 blocks = 24 rows x 32 chunks (8 channels). Wave 0 recomputes the row's
// top-k mask into 128 LDS words; one barrier; all 4 waves stream 32
// vf4/thread in 4 batches of 8: cached loads (L3-resident), bit-select
// (masked-in bits identical; 0.0 vs -0.0 absmax 0), nontemporal stores.
// 3 blocks/CU = 12 waves/CU streaming TLP.
// ---------------------------------------------------------------------------
#define CHB  8
#define BPR  (NC / CHB)          // 32 blocks per row
#define K2B  (NTB * BPR)         // 768
#define VPB  (CHB * HW / 4)      // 8192 vf4 per block
#define VPT  (VPB / 256)         // 32 vf4 per thread

__global__ __launch_bounds__(256, 1) void k_maskapply(const float* __restrict__ i0,
                                                      const float* __restrict__ i1,
                                                      const float* __restrict__ i2,
                                                      const float* __restrict__ imp,
                                                      vf4* __restrict__ out) {
  __shared__ unsigned mbits[HW / 32];          // 128 words = full row mask
  const int blk = blockIdx.x;
  const int row = blk >> 5;                    // 0..23 (t*8+b)
  const int cb  = blk & 31;                    // 8-channel chunk within row
  const int tid = threadIdx.x;

  if (tid < 64) {                              // wave 0: R5 row select
    const int lane = tid;
    const float* base = imp + (size_t)row * HW;
    unsigned u[64];
    const vf4* p = reinterpret_cast<const vf4*>(base + lane * 64);
#pragma unroll
    for (int j = 0; j < 16; ++j) {
      vf4 v = p[j];
      u[4 * j + 0] = __float_as_uint(v.x);
      u[4 * j + 1] = __float_as_uint(v.y);
      u[4 * j + 2] = __float_as_uint(v.z);
      u[4 * j + 3] = __float_as_uint(v.w);
    }
    unsigned mx = 0u, mn = 0xFFFFFFFFu;
#pragma unroll
    for (int j = 0; j < 64; ++j) {
      mx = (u[j] > mx) ? u[j] : mx;
      mn = (u[j] < mn) ? u[j] : mn;
    }
#pragma unroll
    for (int off = 32; off > 0; off >>= 1) {
      unsigned ox = (unsigned)__shfl_xor((int)mx, off, 64);
      unsigned on = (unsigned)__shfl_xor((int)mn, off, 64);
      mx = (ox > mx) ? ox : mx;
      mn = (on < mn) ? on : mn;
    }
    unsigned lo = mn, hi = mx + 1u;            // cnt_ge(lo)>=K, cnt_ge(hi)<K
    while (hi - lo > 1u) {
      unsigned mid = lo + ((hi - lo) >> 1);
      int c = 0;
#pragma unroll
      for (int j = 0; j < 64; ++j) c += (u[j] >= mid);
#pragma unroll
      for (int off = 32; off > 0; off >>= 1) c += __shfl_xor(c, off, 64);
      if (c >= TOPK) lo = mid; else hi = mid;  // c uniform across lanes
    }
    const unsigned thr = lo;
    int eq = 0, gt = 0;
#pragma unroll
    for (int j = 0; j < 64; ++j) {
      eq += (u[j] == thr);
      gt += (u[j] > thr);
    }
    int g_tot = gt;
#pragma unroll
    for (int off = 32; off > 0; off >>= 1) g_tot += __shfl_xor(g_tot, off, 64);
    int incl = eq;
#pragma unroll
    for (int off = 1; off < 64; off <<= 1) {
      int n = __shfl_up(incl, off, 64);
      if (lane >= off) incl += n;
    }
    int r = incl - eq;                         // starting tie-rank, lane order
    const int needed = TOPK - g_tot;
    unsigned w0 = 0u, w1 = 0u;
#pragma unroll
    for (int j = 0; j < 64; ++j) {             // same keep-decision as R5
      unsigned x = u[j];
      int e = (x == thr);
      unsigned keep = (x > thr || (e && r < needed)) ? 1u : 0u;
      if (j < 32) w0 |= keep << j; else w1 |= keep << (j - 32);
      r += e;
    }
    mbits[2 * lane]     = w0;                  // hw [lane*64,    lane*64+32)
    mbits[2 * lane + 1] = w1;                  // hw [lane*64+32, lane*64+64)
  }
  __syncthreads();

  // ---- apply: 8 channels of this row, 32 vf4/thread, 4 batches of 8 ------
  const int t = row >> 3;
  const vf4* src = (t == 0 ? (const vf4*)i0 : (t == 1 ? (const vf4*)i1 : (const vf4*)i2));
  const size_t src_base = ((size_t)(row & 7) * NC + (size_t)cb * CHB) * (HW / 4);
  vf4* obase = out + (size_t)row * NC * (HW / 4) + (size_t)cb * CHB * (HW / 4);
#pragma unroll
  for (int it = 0; it < VPT / 8; ++it) {
    int jj[8];
    vf4 a[8];
    unsigned nib[8];
#pragma unroll
    for (int q = 0; q < 8; ++q) {
      int j = tid + (it * 8 + q) * 256;        // 0..8191 vf4 within chunk
      jj[q] = j;
      a[q] = src[src_base + j];                // cached read (L3-resident)
      int h4 = j & 1023;                       // hw4 (chunk is channel-aligned)
      nib[q] = (mbits[h4 >> 3] >> ((h4 & 7) * 4)) & 15u;
    }
#pragma unroll
    for (int q = 0; q < 8; ++q) {
      vf4 r;
      r.x = (nib[q] & 1u) ? a[q].x : 0.f;
      r.y = (nib[q] & 2u) ? a[q].y : 0.f;
      r.z = (nib[q] & 4u) ? a[q].z : 0.f;
      r.w = (nib[q] & 8u) ? a[q].w : 0.f;
      __builtin_nontemporal_store(r, &obase[jj[q]]);
    }
  }
}

extern "C" void kernel_launch(void* const* d_in, const int* in_sizes, int n_in,
                              void* d_out, int out_size, void* d_ws, size_t ws_size,
                              hipStream_t stream) {
  const float* i0 = (const float*)d_in[0];
  const float* i1 = (const float*)d_in[1];
  const float* i2 = (const float*)d_in[2];
  float* imp = (float*)d_ws;   // 384 KB scratch (imp only; mask stays on-chip)

  k_imp<<<384, 256, 0, stream>>>(i0, i1, i2, imp);
  k_maskapply<<<K2B, 256, 0, stream>>>(i0, i1, i2, imp, (vf4*)d_out);
}

// Round 12
// 69.707 us; speedup vs baseline: 1.0749x; 1.0749x over previous
//
#include <hip/hip_runtime.h>

#define HW   4096      // 64*64
#define NC   256
#define NTB  24        // 3 tensors * 8 batches
#define TOPK 2048      // max(1, int(0.5 * 4096))

typedef float vf4 __attribute__((ext_vector_type(4)));

// ---------------------------------------------------------------------------
// Pass A (R5-proven, ~3.5 us steady-state): imp[tb][hw] = (sum_{c seq} |x|)/256,
// bitwise == np reduce order. Scalar chain/thread, 384 blocks x 256, unroll-32.
// ---------------------------------------------------------------------------
__global__ __launch_bounds__(256) void k_imp(const float* __restrict__ i0,
                                             const float* __restrict__ i1,
                                             const float* __restrict__ i2,
                                             float* __restrict__ imp) {
  int tid = blockIdx.x * 256 + threadIdx.x;   // 0 .. 98303
  int hw  = tid & (HW - 1);
  int tb  = tid >> 12;                        // 0 .. 23
  int t   = tb >> 3;
  const float* base = (t == 0 ? i0 : (t == 1 ? i1 : i2));
  const float* p = base + (size_t)(tb & 7) * NC * HW + hw;
  float s = 0.f;
#pragma unroll 32
  for (int c = 0; c < NC; ++c) s += fabsf(p[c * HW]);  // program order per chain
  imp[tid] = s * (1.0f / 256.0f);             // exact pow2 == /256.0
}

// ---------------------------------------------------------------------------
// Pass B (R5-proven, ~2.5 us): one wave per (t,b); u[64] in registers under
// launch_bounds(64); binary search on uint bits; stable ties. In-place mask.
// ---------------------------------------------------------------------------
__global__ __launch_bounds__(64) void k_select(float* __restrict__ impmask) {
  const int tb   = blockIdx.x;
  float* base    = impmask + (size_t)tb * HW;
  const int lane = threadIdx.x;
  unsigned u[64];
  const vf4* p = reinterpret_cast<const vf4*>(base + lane * 64);
#pragma unroll
  for (int j = 0; j < 16; ++j) {
    vf4 v = p[j];
    u[4 * j + 0] = __float_as_uint(v.x);
    u[4 * j + 1] = __float_as_uint(v.y);
    u[4 * j + 2] = __float_as_uint(v.z);
    u[4 * j + 3] = __float_as_uint(v.w);
  }
  unsigned mx = 0u, mn = 0xFFFFFFFFu;
#pragma unroll
  for (int j = 0; j < 64; ++j) {
    mx = (u[j] > mx) ? u[j] : mx;
    mn = (u[j] < mn) ? u[j] : mn;
  }
#pragma unroll
  for (int off = 32; off > 0; off >>= 1) {
    unsigned ox = (unsigned)__shfl_xor((int)mx, off, 64);
    unsigned on = (unsigned)__shfl_xor((int)mn, off, 64);
    mx = (ox > mx) ? ox : mx;
    mn = (on < mn) ? on : mn;
  }
  unsigned lo = mn, hi = mx + 1u;             // cnt_ge(lo)>=K, cnt_ge(hi)<K
  while (hi - lo > 1u) {
    unsigned mid = lo + ((hi - lo) >> 1);
    int c = 0;
#pragma unroll
    for (int j = 0; j < 64; ++j) c += (u[j] >= mid);
#pragma unroll
    for (int off = 32; off > 0; off >>= 1) c += __shfl_xor(c, off, 64);
    if (c >= TOPK) lo = mid; else hi = mid;   // c uniform across lanes
  }
  const unsigned thr = lo;
  int eq = 0, gt = 0;
#pragma unroll
  for (int j = 0; j < 64; ++j) {
    eq += (u[j] == thr);
    gt += (u[j] > thr);
  }
  int g_tot = gt;
#pragma unroll
  for (int off = 32; off > 0; off >>= 1) g_tot += __shfl_xor(g_tot, off, 64);
  int incl = eq;
#pragma unroll
  for (int off = 1; off < 64; off <<= 1) {
    int n = __shfl_up(incl, off, 64);
    if (lane >= off) incl += n;
  }
  int r = incl - eq;                          // starting tie-rank, lane order
  const int needed = TOPK - g_tot;
  vf4* q = reinterpret_cast<vf4*>(base + lane * 64);
#pragma unroll
  for (int j = 0; j < 16; ++j) {
    float mv[4];
#pragma unroll
    for (int s = 0; s < 4; ++s) {
      unsigned x = u[4 * j + s];
      int e = (x == thr);
      mv[s] = (x > thr || (e && r < needed)) ? 1.f : 0.f;
      r += e;
    }
    vf4 m;
    m.x = mv[0]; m.y = mv[1]; m.z = mv[2]; m.w = mv[3];
    q[j] = m;
  }
}

// ---------------------------------------------------------------------------
// Pass C (R7-measured 23.2 us): grid-stride 2048 blocks x 256 (8 blocks/CU,
// 32 waves/CU), 12 vf4/thread in 3 batches of 4 in-flight, CACHED input
// loads (L3-resident — R6 FETCH=99MB & R7 FETCH=50MB/5reps proofs), mask
// cached (384 KB, L2-hot), nontemporal stores.
// ---------------------------------------------------------------------------
#define APPLY_BLOCKS 2048
#define APPLY_STRIDE (APPLY_BLOCKS * 256)
__global__ __launch_bounds__(256) void k_apply(const vf4* __restrict__ i0,
                                               const vf4* __restrict__ i1,
                                               const vf4* __restrict__ i2,
                                               const vf4* __restrict__ mask,
                                               vf4* __restrict__ out) {
  const int base_idx = blockIdx.x * 256 + threadIdx.x;
  // total vf4 = 24*256*1024 = 6291456 = APPLY_STRIDE * 12 exactly
#pragma unroll
  for (int it = 0; it < 3; ++it) {
    int idx[4];
    vf4 a[4], m[4];
#pragma unroll
    for (int q = 0; q < 4; ++q) {
      int i = base_idx + (it * 4 + q) * APPLY_STRIDE;
      idx[q] = i;
      int tb = i >> 18;                       // 2^18 vf4 per (t,b)
      int t  = tb >> 3;
      const vf4* src = (t == 0 ? i0 : (t == 1 ? i1 : i2));
      a[q] = src[i - (t << 21)];              // cached read (L3-resident)
      m[q] = mask[(tb << 10) | (i & 1023)];
    }
#pragma unroll
    for (int q = 0; q < 4; ++q) {
      vf4 r = a[q] * m[q];
      __builtin_nontemporal_store(r, &out[idx[q]]);
    }
  }
}

extern "C" void kernel_launch(void* const* d_in, const int* in_sizes, int n_in,
                              void* d_out, int out_size, void* d_ws, size_t ws_size,
                              hipStream_t stream) {
  const float* i0 = (const float*)d_in[0];
  const float* i1 = (const float*)d_in[1];
  const float* i2 = (const float*)d_in[2];
  float* imp = (float*)d_ws;   // 384 KB scratch: imp -> mask in place

  k_imp<<<384, 256, 0, stream>>>(i0, i1, i2, imp);
  k_select<<<NTB, 64, 0, stream>>>(imp);
  k_apply<<<APPLY_BLOCKS, 256, 0, stream>>>((const vf4*)i0, (const vf4*)i1,
                                            (const vf4*)i2, (const vf4*)imp,
                                            (vf4*)d_out);
}

// Round 13
// 63.257 us; speedup vs baseline: 1.1845x; 1.1020x over previous
//
#include <hip/hip_runtime.h>

#define HW   4096      // 64*64
#define NC   256
#define NTB  24        // 3 tensors * 8 batches
#define TOPK 2048      // max(1, int(0.5 * 4096))

typedef float vf4 __attribute__((ext_vector_type(4)));

// ---------------------------------------------------------------------------
// K1 (pass A): imp[tb][hw] = (sum_{c seq} |x|)/256, bitwise == np reduce order.
// R5-proven. HBM-cold every replay (inter-replay harness fill wipes L3), so
// ~14.5 us is near the 96 MB read floor.
// ---------------------------------------------------------------------------
__global__ __launch_bounds__(256) void k_imp(const float* __restrict__ i0,
                                             const float* __restrict__ i1,
                                             const float* __restrict__ i2,
                                             float* __restrict__ imp) {
  int tid = blockIdx.x * 256 + threadIdx.x;   // 0 .. 98303
  int hw  = tid & (HW - 1);
  int tb  = tid >> 12;                        // 0 .. 23
  int t   = tb >> 3;
  const float* base = (t == 0 ? i0 : (t == 1 ? i1 : i2));
  const float* p = base + (size_t)(tb & 7) * NC * HW + hw;
  float s = 0.f;
#pragma unroll 32
  for (int c = 0; c < NC; ++c) s += fabsf(p[c * HW]);  // program order per chain
  imp[tid] = s * (1.0f / 256.0f);             // exact pow2 == /256.0
}

// ---------------------------------------------------------------------------
// K2 (select+apply, occupancy-safe): 768 blocks x 256 thr = (row, 8-channel
// chunk). Select DISTRIBUTED over 256 threads: u[16]/thread (16 VGPR -> no
// spill at default budget; R9's u[64]-in-56-VGPR spill structurally
// impossible). Same proven binary-search-on-uint-bits math; per-iter count =
// wave shfl_xor reduce + ping-pong LDS cross-wave sum (1 barrier/iter).
// Stable ties: thread t owns hw [16t,16t+16) -> thread order = index order;
// wave scan + cross-wave prefix gives each thread its tie-rank base.
// Mask -> 256 LDS ushorts; apply streams 32 vf4/thread (4-deep batches,
// R7-proven shape): cached loads (input L3-resident after K1), bit-select,
// nontemporal stores. imp is read-only here (no in-place mask pass).
// ---------------------------------------------------------------------------
#define CHB  8
#define BPR  (NC / CHB)          // 32 blocks per row
#define K2B  (NTB * BPR)         // 768
#define VPT  (CHB * HW / 4 / 256) // 32 vf4 per thread

__global__ __launch_bounds__(256) void k_selapply(const float* __restrict__ i0,
                                                  const float* __restrict__ i1,
                                                  const float* __restrict__ i2,
                                                  const float* __restrict__ imp,
                                                  vf4* __restrict__ out) {
  __shared__ unsigned short mhalf[256];        // 4096-bit row mask
  __shared__ unsigned smn[4], smx[4];
  __shared__ int scnt[2][4];                   // ping-pong per-wave counts
  __shared__ int sgt[4], seq[4];
  const int blk  = blockIdx.x;
  const int row  = blk >> 5;                   // 0..23 (t*8+b)
  const int cb   = blk & 31;                   // 8-channel chunk within row
  const int tid  = threadIdx.x;
  const int lane = tid & 63;
  const int wv   = tid >> 6;

  // ---- load this thread's 16 consecutive imp values (4 x vf4) ------------
  unsigned u[16];
  {
    const vf4* p = reinterpret_cast<const vf4*>(imp + (size_t)row * HW) + tid * 4;
#pragma unroll
    for (int j = 0; j < 4; ++j) {
      vf4 v = p[j];
      u[4 * j + 0] = __float_as_uint(v.x);
      u[4 * j + 1] = __float_as_uint(v.y);
      u[4 * j + 2] = __float_as_uint(v.z);
      u[4 * j + 3] = __float_as_uint(v.w);
    }
  }

  // ---- block min/max prescan ----------------------------------------------
  unsigned mx = 0u, mn = 0xFFFFFFFFu;
#pragma unroll
  for (int j = 0; j < 16; ++j) {
    mx = (u[j] > mx) ? u[j] : mx;
    mn = (u[j] < mn) ? u[j] : mn;
  }
#pragma unroll
  for (int off = 32; off > 0; off >>= 1) {
    unsigned ox = (unsigned)__shfl_xor((int)mx, off, 64);
    unsigned on = (unsigned)__shfl_xor((int)mn, off, 64);
    mx = (ox > mx) ? ox : mx;
    mn = (on < mn) ? on : mn;
  }
  if (lane == 0) { smn[wv] = mn; smx[wv] = mx; }
  __syncthreads();
#pragma unroll
  for (int w = 0; w < 4; ++w) {
    mn = (smn[w] < mn) ? smn[w] : mn;
    mx = (smx[w] > mx) ? smx[w] : mx;
  }

  // ---- binary search k-th largest on uint bits (uniform trip count) ------
  unsigned lo = mn, hi = mx + 1u;              // cnt_ge(lo)>=K, cnt_ge(hi)<K
  int pp = 0;
  while (hi - lo > 1u) {
    unsigned mid = lo + ((hi - lo) >> 1);
    int c = 0;
#pragma unroll
    for (int j = 0; j < 16; ++j) c += (u[j] >= mid);
#pragma unroll
    for (int off = 32; off > 0; off >>= 1) c += __shfl_xor(c, off, 64);
    if (lane == 0) scnt[pp][wv] = c;
    __syncthreads();                           // ping-pong: 1 barrier/iter
    c = scnt[pp][0] + scnt[pp][1] + scnt[pp][2] + scnt[pp][3];  // uniform
    pp ^= 1;
    if (c >= TOPK) lo = mid; else hi = mid;
  }
  const unsigned thr = lo;

  // ---- counts + stable tie-rank (thread order == index order) ------------
  int eq = 0, gt = 0;
#pragma unroll
  for (int j = 0; j < 16; ++j) {
    eq += (u[j] == thr);
    gt += (u[j] > thr);
  }
  int g = gt;
#pragma unroll
  for (int off = 32; off > 0; off >>= 1) g += __shfl_xor(g, off, 64);
  int incl = eq;                               // wave-inclusive scan of eq
#pragma unroll
  for (int off = 1; off < 64; off <<= 1) {
    int n = __shfl_up(incl, off, 64);
    if (lane >= off) incl += n;
  }
  if (lane == 0) sgt[wv] = g;
  if (lane == 63) seq[wv] = incl;
  __syncthreads();
  const int g_tot = sgt[0] + sgt[1] + sgt[2] + sgt[3];
  int eqbase = 0;
#pragma unroll
  for (int w = 0; w < 4; ++w) eqbase += (w < wv) ? seq[w] : 0;
  int r = eqbase + incl - eq;                  // exclusive prefix, this thread
  const int needed = TOPK - g_tot;             // >=1 by search invariant

  // ---- emit 16-bit mask slice ---------------------------------------------
  unsigned bits = 0u;
#pragma unroll
  for (int s = 0; s < 16; ++s) {
    unsigned x = u[s];
    int e = (x == thr);
    unsigned keep = (x > thr || (e && r < needed)) ? 1u : 0u;
    bits |= keep << s;
    r += e;
  }
  mhalf[tid] = (unsigned short)bits;
  __syncthreads();

  // ---- apply: 8 channels of this row, 32 vf4/thread, 8 batches of 4 ------
  const int t = row >> 3;
  const vf4* src = (t == 0 ? (const vf4*)i0 : (t == 1 ? (const vf4*)i1 : (const vf4*)i2));
  const size_t src_base = ((size_t)(row & 7) * NC + (size_t)cb * CHB) * (HW / 4);
  vf4* obase = out + (size_t)row * NC * (HW / 4) + (size_t)cb * CHB * (HW / 4);
#pragma unroll
  for (int it = 0; it < VPT / 4; ++it) {
    int jj[4];
    vf4 a[4];
    unsigned nib[4];
#pragma unroll
    for (int q = 0; q < 4; ++q) {
      int j = tid + (it * 4 + q) * 256;        // 0..8191 vf4 within chunk
      jj[q] = j;
      a[q] = src[src_base + j];                // cached read (L3-resident)
      int h4 = j & 1023;                       // vf4 col within row
      nib[q] = ((unsigned)mhalf[h4 >> 2] >> ((h4 & 3) * 4)) & 15u;
    }
#pragma unroll
    for (int q = 0; q < 4; ++q) {
      vf4 rr;
      rr.x = (nib[q] & 1u) ? a[q].x : 0.f;
      rr.y = (nib[q] & 2u) ? a[q].y : 0.f;
      rr.z = (nib[q] & 4u) ? a[q].z : 0.f;
      rr.w = (nib[q] & 8u) ? a[q].w : 0.f;
      __builtin_nontemporal_store(rr, &obase[jj[q]]);
    }
  }
}

extern "C" void kernel_launch(void* const* d_in, const int* in_sizes, int n_in,
                              void* d_out, int out_size, void* d_ws, size_t ws_size,
                              hipStream_t stream) {
  const float* i0 = (const float*)d_in[0];
  const float* i1 = (const float*)d_in[1];
  const float* i2 = (const float*)d_in[2];
  float* imp = (float*)d_ws;   // 384 KB scratch (imp only; mask stays on-chip)

  k_imp<<<384, 256, 0, stream>>>(i0, i1, i2, imp);
  k_selapply<<<K2B, 256, 0, stream>>>(i0, i1, i2, imp, (vf4*)d_out);
}